// Round 5
// baseline (1806.470 us; speedup 1.0000x reference)
//
#include <hip/hip_runtime.h>
#include <math.h>

#define N_EDGES 4096
#define NN1 256
#define NN2 128

// ---------------- reduction helpers ----------------
template<int NT>
__device__ inline float block_sum(float v, float* red, int t){
  red[t] = v; __syncthreads();
  #pragma unroll
  for (int st = NT/2; st > 0; st >>= 1){
    if (t < st) red[t] += red[t+st];
    __syncthreads();
  }
  float r = red[0]; __syncthreads();
  return r;
}
template<int NT>
__device__ inline float block_max(float v, float* red, int t){
  red[t] = v; __syncthreads();
  #pragma unroll
  for (int st = NT/2; st > 0; st >>= 1){
    if (t < st) red[t] = fmaxf(red[t], red[t+st]);
    __syncthreads();
  }
  float r = red[0]; __syncthreads();
  return r;
}
template<int NT>
__device__ inline int block_min_int(int v, int* red, int t){
  red[t] = v; __syncthreads();
  #pragma unroll
  for (int st = NT/2; st > 0; st >>= 1){
    if (t < st) red[t] = min(red[t], red[t+st]);
    __syncthreads();
  }
  int r = red[0]; __syncthreads();
  return r;
}

// ---------------- conv3x3(SAME), async double-buffered staging ----------------
// Block 256 thr = 4 waves; block tile = 16x16 conv (8x8 pooled); NC couts/block
// (wave owns NC/4, thread NC/4 couts x 4 conv pts). Input either pre-padded
// (PADIN: [CIN][H+2][in_row] with zero border, float4 staging, T14 prefetch)
// or raw with bounds checks (L1 only, single chunk).
// SPLITK==1: fused bias+relu+pool2x2 -> padded interior pointer out
//            (out[cout*out_ch + oy*out_row + ox]).
// SPLITK>1 : raw conv partials [split][COUT][H][W].
template<int CIN, int COUT, int NC, int CHUNK, int SPLITK, bool PADIN>
__global__ __launch_bounds__(256, 4) void conv5(
    const float* __restrict__ in, const float* __restrict__ w,
    const float* __restrict__ bias, float* __restrict__ out,
    int H, int W, int in_row, int in_ch, int out_row, int out_ch)
{
  constexpr int CPB  = CIN / SPLITK;
  constexpr int NCH  = CPB / CHUNK;        // chunks per block
  constexpr int CPT  = NC / 4;             // couts per thread
  constexpr int TROW = 28;                 // padded LDS row (floats)
  constexpr int TSZ  = CHUNK * 18 * TROW;
  constexpr int WSZ  = CHUNK * NC * 12;
  constexpr int TJ   = CHUNK * 90;         // float4 tile jobs (rows*5)
  constexpr int WN   = CHUNK * NC * 9;     // weight floats per chunk
  constexpr int CGRPS = COUT / NC;
  __shared__ float tile[2][TSZ];
  __shared__ float wlds[2][WSZ];

  const int split = blockIdx.z / CGRPS;
  const int cg    = blockIdx.z % CGRPS;
  const int bx = blockIdx.x, by = blockIdx.y;
  const int tid = threadIdx.x;
  const int lane = tid & 63;
  const int wv = tid >> 6;
  const int px = lane & 7, py = lane >> 3;
  const int c_base = split * CPB;

  float acc[CPT][4];
  #pragma unroll
  for (int co = 0; co < CPT; ++co){
    acc[co][0]=0.f; acc[co][1]=0.f; acc[co][2]=0.f; acc[co][3]=0.f;
  }

  float4 s0 = {0,0,0,0}, s1 = {0,0,0,0};
  float wr0 = 0.f, wr1 = 0.f, wr2 = 0.f;

  auto stage_load = [&](int c0){
    if (PADIN){
      if (tid < TJ){
        int row = tid / 5, part = tid - row*5;
        int c = row / 18, rr = row - c*18;
        s0 = *(const float4*)&in[(size_t)(c_base+c0+c)*in_ch
                                 + (size_t)(16*by+rr)*in_row + 16*bx + 4*part];
      }
      int j2 = tid + 256;
      if (j2 < TJ){
        int row = j2 / 5, part = j2 - row*5;
        int c = row / 18, rr = row - c*18;
        s1 = *(const float4*)&in[(size_t)(c_base+c0+c)*in_ch
                                 + (size_t)(16*by+rr)*in_row + 16*bx + 4*part];
      }
    }
    if (tid < WN){
      int co = tid/(CHUNK*9); int r = tid - co*CHUNK*9; int c = r/9; int k = r - c*9;
      wr0 = w[((size_t)(cg*NC+co)*CIN + c_base+c0+c)*9 + k];
    }
    int e = tid + 256;
    if (e < WN){
      int co = e/(CHUNK*9); int r = e - co*CHUNK*9; int c = r/9; int k = r - c*9;
      wr1 = w[((size_t)(cg*NC+co)*CIN + c_base+c0+c)*9 + k];
    }
    e = tid + 512;
    if (e < WN){
      int co = e/(CHUNK*9); int r = e - co*CHUNK*9; int c = r/9; int k = r - c*9;
      wr2 = w[((size_t)(cg*NC+co)*CIN + c_base+c0+c)*9 + k];
    }
  };
  auto stage_write = [&](int b){
    if (PADIN){
      if (tid < TJ){
        int row = tid / 5, part = tid - row*5;
        *(float4*)&tile[b][row*TROW + 4*part] = s0;
      }
      int j2 = tid + 256;
      if (j2 < TJ){
        int row = j2 / 5, part = j2 - row*5;
        *(float4*)&tile[b][row*TROW + 4*part] = s1;
      }
    }
    if (tid < WN){
      int co = tid/(CHUNK*9); int r = tid - co*CHUNK*9; int c = r/9; int k = r - c*9;
      wlds[b][(c*NC+co)*12 + k] = wr0;
    }
    int e = tid + 256;
    if (e < WN){
      int co = e/(CHUNK*9); int r = e - co*CHUNK*9; int c = r/9; int k = r - c*9;
      wlds[b][(c*NC+co)*12 + k] = wr1;
    }
    e = tid + 512;
    if (e < WN){
      int co = e/(CHUNK*9); int r = e - co*CHUNK*9; int c = r/9; int k = r - c*9;
      wlds[b][(c*NC+co)*12 + k] = wr2;
    }
  };
  auto compute = [&](int b){
    #pragma unroll
    for (int c = 0; c < CHUNK; ++c){
      float p[4][4];
      const int tb = (c*18 + 2*py)*TROW + 2*px;
      #pragma unroll
      for (int i = 0; i < 4; ++i){
        float2 lo = *(const float2*)&tile[b][tb + i*TROW];
        float2 hi = *(const float2*)&tile[b][tb + i*TROW + 2];
        p[i][0]=lo.x; p[i][1]=lo.y; p[i][2]=hi.x; p[i][3]=hi.y;
      }
      #pragma unroll
      for (int co = 0; co < CPT; ++co){
        const float* wp = &wlds[b][(c*NC + wv*CPT + co)*12];
        float4 qa = *(const float4*)&wp[0];
        float4 qb = *(const float4*)&wp[4];
        float w8 = wp[8];
        acc[co][0] += qa.x*p[0][0]+qa.y*p[0][1]+qa.z*p[0][2] + qa.w*p[1][0]+qb.x*p[1][1]+qb.y*p[1][2] + qb.z*p[2][0]+qb.w*p[2][1]+w8*p[2][2];
        acc[co][1] += qa.x*p[0][1]+qa.y*p[0][2]+qa.z*p[0][3] + qa.w*p[1][1]+qb.x*p[1][2]+qb.y*p[1][3] + qb.z*p[2][1]+qb.w*p[2][2]+w8*p[2][3];
        acc[co][2] += qa.x*p[1][0]+qa.y*p[1][1]+qa.z*p[1][2] + qa.w*p[2][0]+qb.x*p[2][1]+qb.y*p[2][2] + qb.z*p[3][0]+qb.w*p[3][1]+w8*p[3][2];
        acc[co][3] += qa.x*p[1][1]+qa.y*p[1][2]+qa.z*p[1][3] + qa.w*p[2][1]+qb.x*p[2][2]+qb.y*p[2][3] + qb.z*p[3][1]+qb.w*p[3][2]+w8*p[3][3];
      }
    }
  };

  if (!PADIN){
    // L1: bounds-checked direct staging, single chunk (CHUNK==CIN)
    for (int e = tid; e < CIN*324; e += 256){
      int c = e / 324; int r = e - c*324; int rr = r / 18; int cc = r - rr*18;
      int yy = 16*by - 1 + rr, xx = 16*bx - 1 + cc;
      float v = 0.f;
      if ((unsigned)yy < (unsigned)H && (unsigned)xx < (unsigned)W)
        v = in[(size_t)c*H*W + (size_t)yy*W + xx];
      tile[0][(c*18+rr)*TROW + cc] = v;
    }
    for (int e = tid; e < CIN*NC*9; e += 256){
      int co = e/(CIN*9); int r = e - co*CIN*9; int c = r/9; int k = r - c*9;
      wlds[0][(c*NC+co)*12 + k] = w[((size_t)(cg*NC+co)*CIN + c)*9 + k];
    }
    __syncthreads();
    compute(0);
  } else {
    stage_load(0);
    stage_write(0);
    __syncthreads();
    for (int ch = 0; ch < NCH; ++ch){
      if (ch + 1 < NCH) stage_load((ch+1)*CHUNK);   // global loads in flight
      compute(ch & 1);
      __syncthreads();
      if (ch + 1 < NCH){
        stage_write((ch+1) & 1);                    // vmcnt wait lands here
        __syncthreads();
      }
    }
  }

  if (SPLITK == 1){
    #pragma unroll
    for (int co = 0; co < CPT; ++co){
      int cout = cg*NC + wv*CPT + co;
      float m = fmaxf(fmaxf(acc[co][0],acc[co][1]), fmaxf(acc[co][2],acc[co][3])) + bias[cout];
      int oy = 8*by + py, ox = 8*bx + px;
      out[(size_t)cout*out_ch + (size_t)oy*out_row + ox] = fmaxf(m, 0.f);
    }
  } else {
    #pragma unroll
    for (int co = 0; co < CPT; ++co){
      int cout = cg*NC + wv*CPT + co;
      float* pb = out + ((size_t)split*COUT + cout)*H*W;
      int y0 = 16*by + 2*py, x0 = 16*bx + 2*px;
      *(float2*)&pb[(size_t)y0*W + x0]     = make_float2(acc[co][0], acc[co][1]);
      *(float2*)&pb[(size_t)(y0+1)*W + x0] = make_float2(acc[co][2], acc[co][3]);
    }
  }
}

// sum fp32 partials over splits, then bias + relu + maxpool2x2 (unpadded out)
template<int SPLITK>
__global__ __launch_bounds__(256) void reduce_pool(
    const float* __restrict__ pbuf, const float* __restrict__ bias,
    float* __restrict__ out, int COUT, int H, int W)
{
  int idx = blockIdx.x*256 + threadIdx.x;
  const int OW = W >> 1, OH = H >> 1;
  if (idx >= COUT*OH*OW) return;
  int px = idx % OW; int t = idx / OW; int py = t % OH; int cout = t / OH;
  size_t base = (size_t)cout*H*W + (size_t)(2*py)*W + 2*px;
  size_t sstr = (size_t)COUT*H*W;
  float s00=0.f, s01=0.f, s10=0.f, s11=0.f;
  #pragma unroll
  for (int s=0;s<SPLITK;s++){
    const float* pb = pbuf + s*sstr + base;
    s00 += pb[0]; s01 += pb[1]; s10 += pb[W]; s11 += pb[W+1];
  }
  float m = fmaxf(fmaxf(s00,s01),fmaxf(s10,s11)) + bias[cout];
  out[idx] = fmaxf(m, 0.f);
}

// ---------------- graph kernels ----------------
__global__ void build_adj_kernel(const int* __restrict__ ei, float* adj, float* cnt){
  int e = blockIdx.x*256 + threadIdx.x;
  if (e < N_EDGES){
    int s = ei[e], d = ei[N_EDGES + e];
    atomicAdd(&adj[s*NN1 + d], 1.0f);   // integer-valued -> order independent
    atomicAdd(&cnt[d], 1.0f);
  }
}

// transpose the 4 sage weight matrices [128][256] -> [256][128], packed
__global__ void transpose4_kernel(const float* __restrict__ a, const float* __restrict__ b,
    const float* __restrict__ c, const float* __restrict__ d, float* __restrict__ o){
  int m = blockIdx.y, k = blockIdx.x, cc = threadIdx.x;  // 128 thr
  const float* src = (m==0)?a:(m==1)?b:(m==2)?c:d;
  o[(size_t)m*32768 + k*128 + cc] = src[cc*256 + k];
}

__global__ __launch_bounds__(256) void agg_kernel(const float* __restrict__ adj,
    const float* __restrict__ cnt, const float* __restrict__ org, float* __restrict__ aggn){
  int d = blockIdx.x, j = threadIdx.x;
  float acc = 0.f;
  for (int s = 0; s < NN1; ++s){
    float a = adj[s*NN1 + d];
    if (a != 0.f) acc += a * org[s*NN1 + j];
  }
  aggn[d*NN1 + j] = acc / fmaxf(cnt[d], 1.0f);
}

// transposed-weight sage12: coalesced weight reads; also writes s^T
__global__ __launch_bounds__(128) void sage12_kernel(
    const float* __restrict__ aggn, const float* __restrict__ org,
    const float* __restrict__ wl1t, const float* __restrict__ bl1, const float* __restrict__ wr1t,
    const float* __restrict__ wl2t, const float* __restrict__ bl2, const float* __restrict__ wr2t,
    float* __restrict__ x1, float* __restrict__ s_out, float* __restrict__ st,
    float* __restrict__ entpart)
{
  __shared__ float sa[NN1], so[NN1], red[128];
  int n = blockIdx.x, c = threadIdx.x;
  for (int k = c; k < NN1; k += 128){ sa[k] = aggn[n*NN1+k]; so[k] = org[n*NN1+k]; }
  __syncthreads();
  float p1 = bl1[c], p2 = bl2[c];
  for (int k = 0; k < NN1; ++k){
    float av = sa[k], ov = so[k];
    p1 += av*wl1t[k*128+c] + ov*wr1t[k*128+c];
    p2 += av*wl2t[k*128+c] + ov*wr2t[k*128+c];
  }
  float n1s = block_sum<128>(p1*p1, red, c);
  x1[n*128 + c] = p1 / fmaxf(sqrtf(n1s), 1e-12f);
  float n2s = block_sum<128>(p2*p2, red, c);
  float p2n = p2 / fmaxf(sqrtf(n2s), 1e-12f);
  float mx = block_max<128>(p2n, red, c);
  float ev = expf(p2n - mx);
  float ssum = block_sum<128>(ev, red, c);
  float sv = ev / ssum;
  s_out[n*128 + c] = sv;
  st[c*NN1 + n] = sv;
  float esum = block_sum<128>(-sv * logf(sv + 1e-15f), red, c);
  if (c == 0) entpart[n] = esum;
}

__global__ __launch_bounds__(128) void xp_kernel(const float* __restrict__ s,
    const float* __restrict__ x1, float* __restrict__ xp){
  int cc = blockIdx.x, f = threadIdx.x;
  float acc = 0.f;
  for (int n = 0; n < NN1; ++n) acc += s[n*128+cc] * x1[n*128+f];
  xp[cc*128+f] = acc;
}

__global__ __launch_bounds__(128) void adj_s_kernel(const float* __restrict__ adj,
    const float* __restrict__ s, float* __restrict__ t){
  int n = blockIdx.x, c = threadIdx.x;
  float acc = 0.f;
  for (int m = 0; m < NN1; ++m){
    float a = adj[n*NN1+m];
    if (a != 0.f) acc += a * s[m*128+c];
  }
  t[n*128+c] = acc;
}

__global__ __launch_bounds__(128) void adjp_kernel(const float* __restrict__ s,
    const float* __restrict__ t, float* __restrict__ adjp){
  int cc = blockIdx.x, d = threadIdx.x;
  float acc = 0.f;
  for (int n = 0; n < NN1; ++n) acc += s[n*128+cc] * t[n*128+d];
  adjp[cc*128+d] = acc;
}

// per-row n: sum_m (adj[n][m] - s[n]·s[m])^2 ; uses s^T for coalesced reads
__global__ __launch_bounds__(256) void link_kernel(const float* __restrict__ adj,
    const float* __restrict__ s, const float* __restrict__ st, float* __restrict__ linkpart){
  __shared__ float sn[128]; __shared__ float red[256];
  int n = blockIdx.x, m = threadIdx.x;
  if (m < 128) sn[m] = s[n*128+m];
  __syncthreads();
  float dot = 0.f;
  for (int c = 0; c < 128; ++c) dot += sn[c]*st[c*NN1 + m];
  float v = adj[n*NN1+m] - dot;
  float part = block_sum<256>(v*v, red, m);
  if (m == 0) linkpart[n] = part;
}

__global__ __launch_bounds__(128) void binarize_kernel(const float* __restrict__ adjp,
    float* __restrict__ edge_out, float* __restrict__ ei2_out, int* __restrict__ cols){
  __shared__ float red[128]; __shared__ int redi[128];
  int i = blockIdx.x, j = threadIdx.x;
  float v = adjp[i*128+j];
  float mx = block_max<128>(v, red, j);
  edge_out[i*128+j] = (v == mx) ? 1.0f : 0.0f;
  int cand = (v == mx) ? j : (1 << 30);
  int cmin = block_min_int<128>(cand, redi, j);
  if (j == 0){
    cols[i] = cmin;
    ei2_out[i] = (float)i;
    ei2_out[128 + i] = (float)cmin;
  }
}

__global__ __launch_bounds__(128) void sage3_agg_kernel(const float* __restrict__ xp,
    const int* __restrict__ cols, float* __restrict__ aggn3){
  int d = blockIdx.x, f = threadIdx.x;
  float acc = 0.f, c = 0.f;
  for (int i = 0; i < NN2; ++i){
    if (cols[i] == d){ acc += xp[i*128+f]; c += 1.f; }
  }
  aggn3[d*128+f] = acc / fmaxf(c, 1.f);
}

__global__ __launch_bounds__(128) void sage3_out_kernel(const float* __restrict__ aggn3,
    const float* __restrict__ xp,
    const float* __restrict__ wl3, const float* __restrict__ bl3, const float* __restrict__ wr3,
    float* __restrict__ nodes_out)
{
  __shared__ float red[128];
  int n = blockIdx.x, k = threadIdx.x;
  float ag = aggn3[n*128+k];
  float xv = xp[n*128+k];
  float q0 = block_sum<128>(ag*wl3[k]     + xv*wr3[k],     red, k);
  float q1 = block_sum<128>(ag*wl3[128+k] + xv*wr3[128+k], red, k);
  if (k == 0){
    float p0 = q0 + bl3[0], p1 = q1 + bl3[1];
    float nm = fmaxf(sqrtf(p0*p0 + p1*p1), 1e-12f);
    nodes_out[n*2+0] = tanhf(p0/nm);
    nodes_out[n*2+1] = tanhf(p1/nm);
  }
}

__global__ __launch_bounds__(256) void finalize_kernel(const float* __restrict__ linkpart,
    const float* __restrict__ entpart, float* __restrict__ d_out)
{
  __shared__ float red[256];
  int t = threadIdx.x;
  float ls = block_sum<256>(linkpart[t], red, t);
  float es = block_sum<256>(entpart[t], red, t);
  float v0 = 0.f, v1 = 0.f;
  if (t < 128){ v0 = d_out[4 + t*2 + 0]; v1 = d_out[4 + t*2 + 1]; }
  float s0 = block_sum<256>(v0, red, t);
  float s1 = block_sum<256>(v1, red, t);
  if (t == 0){
    d_out[0] = s0;
    d_out[1] = s1;
    d_out[2] = sqrtf(ls)/65536.0f + sqrtf(16256.0f)/16384.0f;  // ll1 + ll2(const)
    d_out[3] = es/256.0f;                                      // el1 + el2(=0)
  }
}

extern "C" void kernel_launch(void* const* d_in, const int* in_sizes, int n_in,
                              void* d_out_v, int out_size, void* d_ws, size_t ws_size,
                              hipStream_t stream)
{
  (void)in_sizes; (void)n_in; (void)out_size; (void)ws_size;
  const float* input = (const float*)d_in[0];
  const int*   ei    = (const int*)  d_in[1];
  const float* w1 = (const float*)d_in[2];  const float* b1 = (const float*)d_in[3];
  const float* w2 = (const float*)d_in[4];  const float* b2 = (const float*)d_in[5];
  const float* w3 = (const float*)d_in[6];  const float* b3 = (const float*)d_in[7];
  const float* w4 = (const float*)d_in[8];  const float* b4 = (const float*)d_in[9];
  const float* w5 = (const float*)d_in[10]; const float* b5 = (const float*)d_in[11];
  const float* s1wl = (const float*)d_in[12]; const float* s1bl = (const float*)d_in[13];
  const float* s1wr = (const float*)d_in[14];
  const float* s2wl = (const float*)d_in[15]; const float* s2bl = (const float*)d_in[16];
  const float* s2wr = (const float*)d_in[17];
  const float* s3wl = (const float*)d_in[18]; const float* s3bl = (const float*)d_in[19];
  const float* s3wr = (const float*)d_in[20];
  float* d_out = (float*)d_out_v;
  float* ws = (float*)d_ws;

  // Padded buffers [C][H+2][row] with row = align4(W+2); interior at +row+1.
  // P1: 32x258x260  P2: 64x130x132  P3: 128x66x68  P4: 256x34x36
  // workspace (floats), total 4,198,144 = 16.8 MB:
  float* P1 = ws;                     // 2,146,560
  float* P2 = ws + 2146560;           // 1,098,240 (also L5 PART + graph scratch, time-shared)
  float* P3 = ws + 3244800;           //   574,464
  float* P4 = ws + 3819264;           //   313,344
  float* org = ws + 4132608;          //    65,536
  float* PART = P2;                   // 4 x 256 x 32 x 32 = 1,048,576

  // graph scratch (after convs) aliases P2 region
  float* G        = P2;
  float* adj1     = G;                   // 65,536
  float* cnt      = G + 65536;           // 256
  float* aggn3    = G + 65792;           // 16,384
  float* aggn     = G + 82176;           // 65,536
  float* x1       = G + 147712;          // 32,768
  float* s        = G + 180480;          // 32,768
  float* t        = G + 213248;          // 32,768
  float* xp       = G + 246016;          // 16,384
  float* adjp     = G + 262400;          // 16,384
  int*   cols     = (int*)(G + 278784);  // 128
  float* linkpart = G + 278912;          // 256
  float* entpart  = G + 279168;          // 256
  float* wt       = G + 279424;          // 4 x 32,768 transposed sage weights
  float* st       = G + 410496;          // 32,768 (s^T)

  const int p1r = 260, p1c = 258*260;
  const int p2r = 132, p2c = 130*132;
  const int p3r = 68,  p3c = 66*68;
  const int p4r = 36,  p4c = 34*36;

  // zero P1..P4 (borders must be 0 every launch; interiors overwritten)
  hipMemsetAsync(ws, 0, (size_t)4132608*sizeof(float), stream);

  // L1: 5->32 @512 (raw input, bounds-checked) -> P1 interior
  conv5<5,32,16,5,1,false>  <<<dim3(32,32,2),  256, 0, stream>>>(input, w1, b1, P1+p1r+1, 512,512, 0,0, p1r,p1c);
  // L2: 32->64 @256 -> P2 interior
  conv5<32,64,16,4,1,true>  <<<dim3(16,16,4),  256, 0, stream>>>(P1, w2, b2, P2+p2r+1, 256,256, p1r,p1c, p2r,p2c);
  // L3: 64->128 @128 -> P3 interior
  conv5<64,128,16,4,1,true> <<<dim3(8,8,8),    256, 0, stream>>>(P2, w3, b3, P3+p3r+1, 128,128, p2r,p2c, p3r,p3c);
  // L4: 128->256 @64, 8 couts/block -> P4 interior (512 blocks, no split)
  conv5<128,256,8,4,1,true> <<<dim3(4,4,32),   256, 0, stream>>>(P3, w4, b4, P4+p4r+1, 64,64, p3r,p3c, p4r,p4c);
  // L5: 256->256 @32, split-K x4 -> PART, reduce -> org (unpadded 256x16x16)
  conv5<256,256,8,4,4,true> <<<dim3(2,2,128),  256, 0, stream>>>(P4, w5, b5, PART, 32,32, p4r,p4c, 0,0);
  reduce_pool<4>            <<<dim3(256),      256, 0, stream>>>(PART, b5, org, 256, 32, 32);

  // graph tail
  hipMemsetAsync(adj1, 0, (65536 + 256)*sizeof(float), stream);
  transpose4_kernel<<<dim3(256,4), 128, 0, stream>>>(s1wl, s1wr, s2wl, s2wr, wt);
  build_adj_kernel<<<dim3(16),  256, 0, stream>>>(ei, adj1, cnt);
  agg_kernel      <<<dim3(256), 256, 0, stream>>>(adj1, cnt, org, aggn);
  sage12_kernel   <<<dim3(256), 128, 0, stream>>>(aggn, org, wt, s1bl, wt+32768,
                                                  wt+65536, s2bl, wt+98304, x1, s, st, entpart);
  xp_kernel       <<<dim3(128), 128, 0, stream>>>(s, x1, xp);
  adj_s_kernel    <<<dim3(256), 128, 0, stream>>>(adj1, s, t);
  adjp_kernel     <<<dim3(128), 128, 0, stream>>>(s, t, adjp);
  link_kernel     <<<dim3(256), 256, 0, stream>>>(adj1, s, st, linkpart);
  binarize_kernel <<<dim3(128), 128, 0, stream>>>(adjp, d_out + 260, d_out + 16644, cols);
  sage3_agg_kernel<<<dim3(128), 128, 0, stream>>>(xp, cols, aggn3);
  sage3_out_kernel<<<dim3(128), 128, 0, stream>>>(aggn3, xp, s3wl, s3bl, s3wr, d_out + 4);
  finalize_kernel <<<dim3(1),   256, 0, stream>>>(linkpart, entpart, d_out);
}

// Round 6
// 476.617 us; speedup vs baseline: 3.7902x; 3.7902x over previous
//
#include <hip/hip_runtime.h>
#include <math.h>

#define N_EDGES 4096
#define NN1 256
#define NN2 128

// ---------------- reduction helpers ----------------
template<int NT>
__device__ inline float block_sum(float v, float* red, int t){
  red[t] = v; __syncthreads();
  #pragma unroll
  for (int st = NT/2; st > 0; st >>= 1){
    if (t < st) red[t] += red[t+st];
    __syncthreads();
  }
  float r = red[0]; __syncthreads();
  return r;
}
template<int NT>
__device__ inline float block_max(float v, float* red, int t){
  red[t] = v; __syncthreads();
  #pragma unroll
  for (int st = NT/2; st > 0; st >>= 1){
    if (t < st) red[t] = fmaxf(red[t], red[t+st]);
    __syncthreads();
  }
  float r = red[0]; __syncthreads();
  return r;
}
template<int NT>
__device__ inline int block_min_int(int v, int* red, int t){
  red[t] = v; __syncthreads();
  #pragma unroll
  for (int st = NT/2; st > 0; st >>= 1){
    if (t < st) red[t] = min(red[t], red[t+st]);
    __syncthreads();
  }
  int r = red[0]; __syncthreads();
  return r;
}

// ---------------- conv3x3(SAME), single-buffer LDS, uint addressing ----------------
// Block 256 thr = 4 waves; tile = 16x16 conv (8x8 pooled). NC couts/block,
// wave owns NC/4 couts (CPT per thread), thread computes CPT x 4 conv pts.
// Weights staged padded-to-12 -> 2x b128 + 1x b32 LDS reads per cout/channel.
// PADIN: input is [CIN][H+2][in_row] zero-bordered, float4 unchecked staging.
// SPLITK==1: fused bias+relu+pool -> padded interior out (out_row/out_ch pitch).
// SPLITK>1 : raw conv partials [split][COUT][H][W].
template<int CIN, int COUT, int NC, int CHUNK, int SPLITK, bool PADIN>
__global__ __launch_bounds__(256) void conv6(
    const float* __restrict__ in, const float* __restrict__ w,
    const float* __restrict__ bias, float* __restrict__ out,
    unsigned H, unsigned W, unsigned in_row, unsigned in_ch,
    unsigned out_row, unsigned out_ch)
{
  constexpr int CPB  = CIN / SPLITK;
  constexpr int NCH  = CPB / CHUNK;
  constexpr int CPT  = NC / 4;
  constexpr int TROW = 28;                  // 112 B rows: 16B-aligned, bank-friendly
  constexpr int CGRPS = COUT / NC;
  __shared__ float tile[CHUNK][18][TROW];
  __shared__ float wlds[CHUNK][NC][12];

  const unsigned split = blockIdx.z / CGRPS;
  const unsigned cg    = blockIdx.z % CGRPS;
  const unsigned bx = blockIdx.x, by = blockIdx.y;
  const int tid = threadIdx.x;
  const int lane = tid & 63;
  const int wv = tid >> 6;
  const int px = lane & 7, py = lane >> 3;
  const unsigned c_base = split * CPB;

  float acc[CPT][4];
  #pragma unroll
  for (int co = 0; co < CPT; ++co){
    acc[co][0]=0.f; acc[co][1]=0.f; acc[co][2]=0.f; acc[co][3]=0.f;
  }

  for (int c0 = 0; c0 < CPB; c0 += CHUNK){
    __syncthreads();
    if (PADIN){
      constexpr int TJ = CHUNK * 90;        // CHUNK x 18 rows x 5 float4
      for (int j = tid; j < TJ; j += 256){
        int row = j / 5, part = j - row*5;
        int c = row / 18, rr = row - c*18;
        unsigned off = (c_base + c0 + c)*in_ch + (16u*by + rr)*in_row + 16u*bx + 4u*part;
        float4 v = *(const float4*)&in[off];
        *(float4*)&tile[c][rr][4*part] = v;
      }
    } else {
      for (int e = tid; e < CHUNK*324; e += 256){
        int c = e / 324; int r = e - c*324; int rr = r / 18; int cc = r - rr*18;
        int yy = 16*(int)by - 1 + rr, xx = 16*(int)bx - 1 + cc;
        float v = 0.f;
        if ((unsigned)yy < H && (unsigned)xx < W)
          v = in[(unsigned)(c0 + c)*H*W + (unsigned)yy*W + (unsigned)xx];
        tile[c][rr][cc] = v;
      }
    }
    {
      constexpr int WN = CHUNK * NC * 9;
      for (int e = tid; e < WN; e += 256){
        int c = e / (NC*9); int r = e - c*NC*9; int co = r / 9; int k = r - co*9;
        wlds[c][co][k] = w[((cg*NC + co)*CIN + c_base + c0 + c)*9u + k];
      }
    }
    __syncthreads();

    #pragma unroll
    for (int c = 0; c < CHUNK; ++c){
      float p[4][4];
      #pragma unroll
      for (int i = 0; i < 4; ++i){
        float2 lo = *(const float2*)&tile[c][2*py + i][2*px];
        float2 hi = *(const float2*)&tile[c][2*py + i][2*px + 2];
        p[i][0]=lo.x; p[i][1]=lo.y; p[i][2]=hi.x; p[i][3]=hi.y;
      }
      #pragma unroll
      for (int co = 0; co < CPT; ++co){
        const float* wp = &wlds[c][wv*CPT + co][0];
        float4 qa = *(const float4*)&wp[0];
        float4 qb = *(const float4*)&wp[4];
        float w8 = wp[8];
        acc[co][0] += qa.x*p[0][0]+qa.y*p[0][1]+qa.z*p[0][2] + qa.w*p[1][0]+qb.x*p[1][1]+qb.y*p[1][2] + qb.z*p[2][0]+qb.w*p[2][1]+w8*p[2][2];
        acc[co][1] += qa.x*p[0][1]+qa.y*p[0][2]+qa.z*p[0][3] + qa.w*p[1][1]+qb.x*p[1][2]+qb.y*p[1][3] + qb.z*p[2][1]+qb.w*p[2][2]+w8*p[2][3];
        acc[co][2] += qa.x*p[1][0]+qa.y*p[1][1]+qa.z*p[1][2] + qa.w*p[2][0]+qb.x*p[2][1]+qb.y*p[2][2] + qb.z*p[3][0]+qb.w*p[3][1]+w8*p[3][2];
        acc[co][3] += qa.x*p[1][1]+qa.y*p[1][2]+qa.z*p[1][3] + qa.w*p[2][1]+qb.x*p[2][2]+qb.y*p[2][3] + qb.z*p[3][1]+qb.w*p[3][2]+w8*p[3][3];
      }
    }
  }

  if (SPLITK == 1){
    #pragma unroll
    for (int co = 0; co < CPT; ++co){
      unsigned cout = cg*NC + wv*CPT + co;
      float m = fmaxf(fmaxf(acc[co][0],acc[co][1]), fmaxf(acc[co][2],acc[co][3])) + bias[cout];
      unsigned oy = 8u*by + py, ox = 8u*bx + px;
      out[cout*out_ch + oy*out_row + ox] = fmaxf(m, 0.f);
    }
  } else {
    #pragma unroll
    for (int co = 0; co < CPT; ++co){
      unsigned cout = cg*NC + wv*CPT + co;
      float* pb = out + (split*COUT + cout)*H*W;
      unsigned y0 = 16u*by + 2u*py, x0 = 16u*bx + 2u*px;
      *(float2*)&pb[y0*W + x0]     = make_float2(acc[co][0], acc[co][1]);
      *(float2*)&pb[(y0+1)*W + x0] = make_float2(acc[co][2], acc[co][3]);
    }
  }
}

// sum fp32 partials over splits, then bias + relu + maxpool2x2 (unpadded out)
template<int SPLITK>
__global__ __launch_bounds__(256) void reduce_pool(
    const float* __restrict__ pbuf, const float* __restrict__ bias,
    float* __restrict__ out, int COUT, int H, int W)
{
  int idx = blockIdx.x*256 + threadIdx.x;
  const int OW = W >> 1, OH = H >> 1;
  if (idx >= COUT*OH*OW) return;
  int px = idx % OW; int t = idx / OW; int py = t % OH; int cout = t / OH;
  unsigned base = (unsigned)cout*H*W + (unsigned)(2*py)*W + 2*px;
  unsigned sstr = (unsigned)COUT*H*W;
  float s00=0.f, s01=0.f, s10=0.f, s11=0.f;
  #pragma unroll
  for (int s=0;s<SPLITK;s++){
    const float* pb = pbuf + s*sstr + base;
    s00 += pb[0]; s01 += pb[1]; s10 += pb[W]; s11 += pb[W+1];
  }
  float m = fmaxf(fmaxf(s00,s01),fmaxf(s10,s11)) + bias[cout];
  out[idx] = fmaxf(m, 0.f);
}

// ---------------- graph kernels ----------------
__global__ void build_adj_kernel(const int* __restrict__ ei, float* adj, float* cnt){
  int e = blockIdx.x*256 + threadIdx.x;
  if (e < N_EDGES){
    int s = ei[e], d = ei[N_EDGES + e];
    atomicAdd(&adj[s*NN1 + d], 1.0f);   // integer-valued -> order independent
    atomicAdd(&cnt[d], 1.0f);
  }
}

// transpose the 4 sage weight matrices [128][256] -> [256][128], packed
__global__ void transpose4_kernel(const float* __restrict__ a, const float* __restrict__ b,
    const float* __restrict__ c, const float* __restrict__ d, float* __restrict__ o){
  int m = blockIdx.y, k = blockIdx.x, cc = threadIdx.x;  // 128 thr
  const float* src = (m==0)?a:(m==1)?b:(m==2)?c:d;
  o[(size_t)m*32768 + k*128 + cc] = src[cc*256 + k];
}

__global__ __launch_bounds__(256) void agg_kernel(const float* __restrict__ adj,
    const float* __restrict__ cnt, const float* __restrict__ org, float* __restrict__ aggn){
  int d = blockIdx.x, j = threadIdx.x;
  float acc = 0.f;
  for (int s = 0; s < NN1; ++s){
    float a = adj[s*NN1 + d];
    if (a != 0.f) acc += a * org[s*NN1 + j];
  }
  aggn[d*NN1 + j] = acc / fmaxf(cnt[d], 1.0f);
}

// transposed-weight sage12: coalesced weight reads; also writes s^T
__global__ __launch_bounds__(128) void sage12_kernel(
    const float* __restrict__ aggn, const float* __restrict__ org,
    const float* __restrict__ wl1t, const float* __restrict__ bl1, const float* __restrict__ wr1t,
    const float* __restrict__ wl2t, const float* __restrict__ bl2, const float* __restrict__ wr2t,
    float* __restrict__ x1, float* __restrict__ s_out, float* __restrict__ st,
    float* __restrict__ entpart)
{
  __shared__ float sa[NN1], so[NN1], red[128];
  int n = blockIdx.x, c = threadIdx.x;
  for (int k = c; k < NN1; k += 128){ sa[k] = aggn[n*NN1+k]; so[k] = org[n*NN1+k]; }
  __syncthreads();
  float p1 = bl1[c], p2 = bl2[c];
  for (int k = 0; k < NN1; ++k){
    float av = sa[k], ov = so[k];
    p1 += av*wl1t[k*128+c] + ov*wr1t[k*128+c];
    p2 += av*wl2t[k*128+c] + ov*wr2t[k*128+c];
  }
  float n1s = block_sum<128>(p1*p1, red, c);
  x1[n*128 + c] = p1 / fmaxf(sqrtf(n1s), 1e-12f);
  float n2s = block_sum<128>(p2*p2, red, c);
  float p2n = p2 / fmaxf(sqrtf(n2s), 1e-12f);
  float mx = block_max<128>(p2n, red, c);
  float ev = expf(p2n - mx);
  float ssum = block_sum<128>(ev, red, c);
  float sv = ev / ssum;
  s_out[n*128 + c] = sv;
  st[c*NN1 + n] = sv;
  float esum = block_sum<128>(-sv * logf(sv + 1e-15f), red, c);
  if (c == 0) entpart[n] = esum;
}

__global__ __launch_bounds__(128) void xp_kernel(const float* __restrict__ s,
    const float* __restrict__ x1, float* __restrict__ xp){
  int cc = blockIdx.x, f = threadIdx.x;
  float acc = 0.f;
  for (int n = 0; n < NN1; ++n) acc += s[n*128+cc] * x1[n*128+f];
  xp[cc*128+f] = acc;
}

__global__ __launch_bounds__(128) void adj_s_kernel(const float* __restrict__ adj,
    const float* __restrict__ s, float* __restrict__ t){
  int n = blockIdx.x, c = threadIdx.x;
  float acc = 0.f;
  for (int m = 0; m < NN1; ++m){
    float a = adj[n*NN1+m];
    if (a != 0.f) acc += a * s[m*128+c];
  }
  t[n*128+c] = acc;
}

__global__ __launch_bounds__(128) void adjp_kernel(const float* __restrict__ s,
    const float* __restrict__ t, float* __restrict__ adjp){
  int cc = blockIdx.x, d = threadIdx.x;
  float acc = 0.f;
  for (int n = 0; n < NN1; ++n) acc += s[n*128+cc] * t[n*128+d];
  adjp[cc*128+d] = acc;
}

// per-row n: sum_m (adj[n][m] - s[n]·s[m])^2 ; uses s^T for coalesced reads
__global__ __launch_bounds__(256) void link_kernel(const float* __restrict__ adj,
    const float* __restrict__ s, const float* __restrict__ st, float* __restrict__ linkpart){
  __shared__ float sn[128]; __shared__ float red[256];
  int n = blockIdx.x, m = threadIdx.x;
  if (m < 128) sn[m] = s[n*128+m];
  __syncthreads();
  float dot = 0.f;
  for (int c = 0; c < 128; ++c) dot += sn[c]*st[c*NN1 + m];
  float v = adj[n*NN1+m] - dot;
  float part = block_sum<256>(v*v, red, m);
  if (m == 0) linkpart[n] = part;
}

__global__ __launch_bounds__(128) void binarize_kernel(const float* __restrict__ adjp,
    float* __restrict__ edge_out, float* __restrict__ ei2_out, int* __restrict__ cols){
  __shared__ float red[128]; __shared__ int redi[128];
  int i = blockIdx.x, j = threadIdx.x;
  float v = adjp[i*128+j];
  float mx = block_max<128>(v, red, j);
  edge_out[i*128+j] = (v == mx) ? 1.0f : 0.0f;
  int cand = (v == mx) ? j : (1 << 30);
  int cmin = block_min_int<128>(cand, redi, j);
  if (j == 0){
    cols[i] = cmin;
    ei2_out[i] = (float)i;
    ei2_out[128 + i] = (float)cmin;
  }
}

__global__ __launch_bounds__(128) void sage3_agg_kernel(const float* __restrict__ xp,
    const int* __restrict__ cols, float* __restrict__ aggn3){
  int d = blockIdx.x, f = threadIdx.x;
  float acc = 0.f, c = 0.f;
  for (int i = 0; i < NN2; ++i){
    if (cols[i] == d){ acc += xp[i*128+f]; c += 1.f; }
  }
  aggn3[d*128+f] = acc / fmaxf(c, 1.f);
}

__global__ __launch_bounds__(128) void sage3_out_kernel(const float* __restrict__ aggn3,
    const float* __restrict__ xp,
    const float* __restrict__ wl3, const float* __restrict__ bl3, const float* __restrict__ wr3,
    float* __restrict__ nodes_out)
{
  __shared__ float red[128];
  int n = blockIdx.x, k = threadIdx.x;
  float ag = aggn3[n*128+k];
  float xv = xp[n*128+k];
  float q0 = block_sum<128>(ag*wl3[k]     + xv*wr3[k],     red, k);
  float q1 = block_sum<128>(ag*wl3[128+k] + xv*wr3[128+k], red, k);
  if (k == 0){
    float p0 = q0 + bl3[0], p1 = q1 + bl3[1];
    float nm = fmaxf(sqrtf(p0*p0 + p1*p1), 1e-12f);
    nodes_out[n*2+0] = tanhf(p0/nm);
    nodes_out[n*2+1] = tanhf(p1/nm);
  }
}

__global__ __launch_bounds__(256) void finalize_kernel(const float* __restrict__ linkpart,
    const float* __restrict__ entpart, float* __restrict__ d_out)
{
  __shared__ float red[256];
  int t = threadIdx.x;
  float ls = block_sum<256>(linkpart[t], red, t);
  float es = block_sum<256>(entpart[t], red, t);
  float v0 = 0.f, v1 = 0.f;
  if (t < 128){ v0 = d_out[4 + t*2 + 0]; v1 = d_out[4 + t*2 + 1]; }
  float s0 = block_sum<256>(v0, red, t);
  float s1 = block_sum<256>(v1, red, t);
  if (t == 0){
    d_out[0] = s0;
    d_out[1] = s1;
    d_out[2] = sqrtf(ls)/65536.0f + sqrtf(16256.0f)/16384.0f;  // ll1 + ll2(const)
    d_out[3] = es/256.0f;                                      // el1 + el2(=0)
  }
}

extern "C" void kernel_launch(void* const* d_in, const int* in_sizes, int n_in,
                              void* d_out_v, int out_size, void* d_ws, size_t ws_size,
                              hipStream_t stream)
{
  (void)in_sizes; (void)n_in; (void)out_size; (void)ws_size;
  const float* input = (const float*)d_in[0];
  const int*   ei    = (const int*)  d_in[1];
  const float* w1 = (const float*)d_in[2];  const float* b1 = (const float*)d_in[3];
  const float* w2 = (const float*)d_in[4];  const float* b2 = (const float*)d_in[5];
  const float* w3 = (const float*)d_in[6];  const float* b3 = (const float*)d_in[7];
  const float* w4 = (const float*)d_in[8];  const float* b4 = (const float*)d_in[9];
  const float* w5 = (const float*)d_in[10]; const float* b5 = (const float*)d_in[11];
  const float* s1wl = (const float*)d_in[12]; const float* s1bl = (const float*)d_in[13];
  const float* s1wr = (const float*)d_in[14];
  const float* s2wl = (const float*)d_in[15]; const float* s2bl = (const float*)d_in[16];
  const float* s2wr = (const float*)d_in[17];
  const float* s3wl = (const float*)d_in[18]; const float* s3bl = (const float*)d_in[19];
  const float* s3wr = (const float*)d_in[20];
  float* d_out = (float*)d_out_v;
  float* ws = (float*)d_ws;

  // Padded buffers [C][H+2][row], row = W+2 padded to x4; interior at +row+1.
  // P1: 32x258x260  P2: 64x130x132  P3: 128x66x68  P4: 256x34x36
  float* P1 = ws;                     // 2,146,560
  float* P2 = ws + 2146560;           // 1,098,240 (graph scratch aliases after L3)
  float* P3 = ws + 3244800;           //   574,464
  float* P4 = ws + 3819264;           //   313,344
  float* org = ws + 4132608;          //    65,536
  float* PART = P1;                   // L5 partials: 8 x 256 x 32 x 32 = 2,097,152 (P1 dead after L2)

  // graph scratch (after convs) aliases P2 region
  float* G        = P2;
  float* adj1     = G;                   // 65,536
  float* cnt      = G + 65536;           // 256
  float* aggn3    = G + 65792;           // 16,384
  float* aggn     = G + 82176;           // 65,536
  float* x1       = G + 147712;          // 32,768
  float* s        = G + 180480;          // 32,768
  float* t        = G + 213248;          // 32,768
  float* xp       = G + 246016;          // 16,384
  float* adjp     = G + 262400;          // 16,384
  int*   cols     = (int*)(G + 278784);  // 128
  float* linkpart = G + 278912;          // 256
  float* entpart  = G + 279168;          // 256
  float* wt       = G + 279424;          // 4 x 32,768 transposed sage weights
  float* st       = G + 410496;          // 32,768 (s^T)

  const unsigned p1r = 260, p1c = 258*260;
  const unsigned p2r = 132, p2c = 130*132;
  const unsigned p3r = 68,  p3c = 66*68;
  const unsigned p4r = 36,  p4c = 34*36;

  // zero padded buffers (borders must be 0 every launch; interiors overwritten)
  hipMemsetAsync(ws, 0, (size_t)4132608*sizeof(float), stream);

  // L1: 5->32 @512 (raw input, bounds-checked) -> P1 interior   (2048 blocks)
  conv6<5,32,16,5,1,false>  <<<dim3(32,32,2),  256, 0, stream>>>(input, w1, b1, P1+p1r+1, 512,512, 0,0, p1r,p1c);
  // L2: 32->64 @256 -> P2 interior                              (1024 blocks)
  conv6<32,64,16,8,1,true>  <<<dim3(16,16,4),  256, 0, stream>>>(P1, w2, b2, P2+p2r+1, 256,256, p1r,p1c, p2r,p2c);
  // L3: 64->128 @128 -> P3 interior                             (512 blocks)
  conv6<64,128,16,8,1,true> <<<dim3(8,8,8),    256, 0, stream>>>(P2, w3, b3, P3+p3r+1, 128,128, p2r,p2c, p3r,p3c);
  // L4: 128->256 @64, NC=8 -> P4 interior                       (512 blocks, input L2-resident)
  conv6<128,256,8,8,1,true> <<<dim3(4,4,32),   256, 0, stream>>>(P3, w4, b4, P4+p4r+1, 64,64, p3r,p3c, p4r,p4c);
  // L5: 256->256 @32, NC=8 splitK8 -> PART, reduce -> org       (1024 blocks)
  conv6<256,256,8,8,8,true> <<<dim3(2,2,256),  256, 0, stream>>>(P4, w5, b5, PART, 32,32, p4r,p4c, 0,0);
  reduce_pool<8>            <<<dim3(256),      256, 0, stream>>>(PART, b5, org, 256, 32, 32);

  // graph tail
  hipMemsetAsync(adj1, 0, (65536 + 256)*sizeof(float), stream);
  transpose4_kernel<<<dim3(256,4), 128, 0, stream>>>(s1wl, s1wr, s2wl, s2wr, wt);
  build_adj_kernel<<<dim3(16),  256, 0, stream>>>(ei, adj1, cnt);
  agg_kernel      <<<dim3(256), 256, 0, stream>>>(adj1, cnt, org, aggn);
  sage12_kernel   <<<dim3(256), 128, 0, stream>>>(aggn, org, wt, s1bl, wt+32768,
                                                  wt+65536, s2bl, wt+98304, x1, s, st, entpart);
  xp_kernel       <<<dim3(128), 128, 0, stream>>>(s, x1, xp);
  adj_s_kernel    <<<dim3(256), 128, 0, stream>>>(adj1, s, t);
  adjp_kernel     <<<dim3(128), 128, 0, stream>>>(s, t, adjp);
  link_kernel     <<<dim3(256), 256, 0, stream>>>(adj1, s, st, linkpart);
  binarize_kernel <<<dim3(128), 128, 0, stream>>>(adjp, d_out + 260, d_out + 16644, cols);
  sage3_agg_kernel<<<dim3(128), 128, 0, stream>>>(xp, cols, aggn3);
  sage3_out_kernel<<<dim3(128), 128, 0, stream>>>(aggn3, xp, s3wl, s3bl, s3wr, d_out + 4);
  finalize_kernel <<<dim3(1),   256, 0, stream>>>(linkpart, entpart, d_out);
}

// Round 7
// 448.335 us; speedup vs baseline: 4.0293x; 1.0631x over previous
//
#include <hip/hip_runtime.h>
#include <math.h>

#define N_EDGES 4096
#define NN1 256
#define NN2 128

// ---------------- reduction helpers ----------------
template<int NT>
__device__ inline float block_sum(float v, float* red, int t){
  red[t] = v; __syncthreads();
  #pragma unroll
  for (int st = NT/2; st > 0; st >>= 1){
    if (t < st) red[t] += red[t+st];
    __syncthreads();
  }
  float r = red[0]; __syncthreads();
  return r;
}
template<int NT>
__device__ inline float block_max(float v, float* red, int t){
  red[t] = v; __syncthreads();
  #pragma unroll
  for (int st = NT/2; st > 0; st >>= 1){
    if (t < st) red[t] = fmaxf(red[t], red[t+st]);
    __syncthreads();
  }
  float r = red[0]; __syncthreads();
  return r;
}
template<int NT>
__device__ inline int block_min_int(int v, int* red, int t){
  red[t] = v; __syncthreads();
  #pragma unroll
  for (int st = NT/2; st > 0; st >>= 1){
    if (t < st) red[t] = min(red[t], red[t+st]);
    __syncthreads();
  }
  int r = red[0]; __syncthreads();
  return r;
}

// ---------------- conv3x3(SAME), double-buffered register-prefetch staging ----------------
// Block 256 thr = 4 waves; tile = 16x16 conv (8x8 pooled). NC couts/block,
// wave owns CPT=NC/4 couts, thread computes CPT x 4 conv pts.
// Input MUST be pre-padded: [CIN][H+2][in_row], zero border, base pointer.
// Pipeline per chunk: issue global loads for chunk+1 (regs) -> compute chunk
// from LDS -> barrier -> regs->LDS -> barrier. Staging indices hoisted.
// SPLITK==1: fused bias+relu+pool -> padded interior out pointer.
// SPLITK>1 : raw conv partials [split][COUT][H][W].
template<int CIN, int COUT, int NC, int CHUNK, int SPLITK>
__global__ __launch_bounds__(256) void conv7(
    const float* __restrict__ in, const float* __restrict__ w,
    const float* __restrict__ bias, float* __restrict__ out,
    int H, int W, int in_row, int in_ch, int out_row, int out_ch)
{
  constexpr int CPB  = CIN / SPLITK;
  constexpr int NCH  = CPB / CHUNK;
  constexpr int CPT  = NC / 4;
  constexpr int TROW = 28;
  constexpr int CGRPS = COUT / NC;
  constexpr int TSZ  = CHUNK * 18 * TROW;
  constexpr int WSZ  = CHUNK * NC * 12;
  constexpr int TJ   = CHUNK * 90;          // float4 tile jobs (<=512)
  constexpr int WN   = CHUNK * NC * 9;      // weight scalar jobs (<=768)
  __shared__ float tile[2][TSZ];
  __shared__ float wlds[2][WSZ];

  const int split = blockIdx.z / CGRPS;
  const int cg    = blockIdx.z % CGRPS;
  const int bx = blockIdx.x, by = blockIdx.y;
  const int tid = threadIdx.x;
  const int lane = tid & 63;
  const int wv = tid >> 6;
  const int px = lane & 7, py = lane >> 3;
  const int c_base = split * CPB;

  // ---- hoisted staging descriptors (chunk-invariant) ----
  int tsrc0, tlds0, tsrc1 = 0, tlds1 = 0;
  {
    int j = tid, row = j / 5, part = j - row*5, c = row / 18, rr = row - c*18;
    tsrc0 = (c_base + c)*in_ch + (16*by + rr)*in_row + 16*bx + 4*part;
    tlds0 = (c*18 + rr)*TROW + 4*part;
  }
  const bool tv1 = (tid + 256) < TJ;
  if (tv1){
    int j = tid + 256, row = j / 5, part = j - row*5, c = row / 18, rr = row - c*18;
    tsrc1 = (c_base + c)*in_ch + (16*by + rr)*in_row + 16*bx + 4*part;
    tlds1 = (c*18 + rr)*TROW + 4*part;
  }
  int wsrc0, wldo0, wsrc1 = 0, wldo1 = 0, wsrc2 = 0, wldo2 = 0;
  {
    int e = tid, c = e/(NC*9), r = e - c*NC*9, co = r/9, k = r - co*9;
    wsrc0 = ((cg*NC + co)*CIN + c_base + c)*9 + k;
    wldo0 = (c*NC + co)*12 + k;
  }
  const bool wv1 = (tid + 256) < WN;
  if (wv1){
    int e = tid + 256, c = e/(NC*9), r = e - c*NC*9, co = r/9, k = r - co*9;
    wsrc1 = ((cg*NC + co)*CIN + c_base + c)*9 + k;
    wldo1 = (c*NC + co)*12 + k;
  }
  const bool wv2 = (tid + 512) < WN;
  if (wv2){
    int e = tid + 512, c = e/(NC*9), r = e - c*NC*9, co = r/9, k = r - co*9;
    wsrc2 = ((cg*NC + co)*CIN + c_base + c)*9 + k;
    wldo2 = (c*NC + co)*12 + k;
  }

  float acc[CPT][4];
  #pragma unroll
  for (int co = 0; co < CPT; ++co){
    acc[co][0]=0.f; acc[co][1]=0.f; acc[co][2]=0.f; acc[co][3]=0.f;
  }

  float4 rt0, rt1;
  float rw0, rw1, rw2;

  auto LD = [&](int c0){
    rt0 = *(const float4*)&in[tsrc0 + c0*in_ch];
    if (tv1) rt1 = *(const float4*)&in[tsrc1 + c0*in_ch];
    rw0 = w[wsrc0 + c0*9];
    if (wv1) rw1 = w[wsrc1 + c0*9];
    if (wv2) rw2 = w[wsrc2 + c0*9];
  };
  auto ST = [&](int b){
    *(float4*)&tile[b][tlds0] = rt0;
    if (tv1) *(float4*)&tile[b][tlds1] = rt1;
    wlds[b][wldo0] = rw0;
    if (wv1) wlds[b][wldo1] = rw1;
    if (wv2) wlds[b][wldo2] = rw2;
  };
  auto COMPUTE = [&](int b){
    #pragma unroll
    for (int c = 0; c < CHUNK; ++c){
      float p[4][4];
      const int tb = c*18*TROW + 2*py*TROW + 2*px;
      #pragma unroll
      for (int i = 0; i < 4; ++i){
        float2 lo = *(const float2*)&tile[b][tb + i*TROW];
        float2 hi = *(const float2*)&tile[b][tb + i*TROW + 2];
        p[i][0]=lo.x; p[i][1]=lo.y; p[i][2]=hi.x; p[i][3]=hi.y;
      }
      #pragma unroll
      for (int co = 0; co < CPT; ++co){
        const float* wp = &wlds[b][(c*NC + wv*CPT + co)*12];
        float4 qa = *(const float4*)&wp[0];
        float4 qb = *(const float4*)&wp[4];
        float w8 = wp[8];
        acc[co][0] += qa.x*p[0][0]+qa.y*p[0][1]+qa.z*p[0][2] + qa.w*p[1][0]+qb.x*p[1][1]+qb.y*p[1][2] + qb.z*p[2][0]+qb.w*p[2][1]+w8*p[2][2];
        acc[co][1] += qa.x*p[0][1]+qa.y*p[0][2]+qa.z*p[0][3] + qa.w*p[1][1]+qb.x*p[1][2]+qb.y*p[1][3] + qb.z*p[2][1]+qb.w*p[2][2]+w8*p[2][3];
        acc[co][2] += qa.x*p[1][0]+qa.y*p[1][1]+qa.z*p[1][2] + qa.w*p[2][0]+qb.x*p[2][1]+qb.y*p[2][2] + qb.z*p[3][0]+qb.w*p[3][1]+w8*p[3][2];
        acc[co][3] += qa.x*p[1][1]+qa.y*p[1][2]+qa.z*p[1][3] + qa.w*p[2][1]+qb.x*p[2][2]+qb.y*p[2][3] + qb.z*p[3][1]+qb.w*p[3][2]+w8*p[3][3];
      }
    }
  };

  LD(0); ST(0); __syncthreads();
  for (int ch = 0; ch < NCH; ++ch){
    if (ch + 1 < NCH) LD((ch+1)*CHUNK);   // global loads in flight under compute
    COMPUTE(ch & 1);
    __syncthreads();
    if (ch + 1 < NCH){
      ST((ch+1) & 1);
      __syncthreads();
    }
  }

  if (SPLITK == 1){
    #pragma unroll
    for (int co = 0; co < CPT; ++co){
      int cout = cg*NC + wv*CPT + co;
      float m = fmaxf(fmaxf(acc[co][0],acc[co][1]), fmaxf(acc[co][2],acc[co][3])) + bias[cout];
      int oy = 8*by + py, ox = 8*bx + px;
      out[cout*out_ch + oy*out_row + ox] = fmaxf(m, 0.f);
    }
  } else {
    #pragma unroll
    for (int co = 0; co < CPT; ++co){
      int cout = cg*NC + wv*CPT + co;
      float* pb = out + (split*COUT + cout)*H*W;
      int y0 = 16*by + 2*py, x0 = 16*bx + 2*px;
      *(float2*)&pb[y0*W + x0]     = make_float2(acc[co][0], acc[co][1]);
      *(float2*)&pb[(y0+1)*W + x0] = make_float2(acc[co][2], acc[co][3]);
    }
  }
}

// copy raw 5x512x512 input into zero-bordered P0 [5][514][516]
__global__ __launch_bounds__(256) void pad_copy(const float* __restrict__ src,
                                                float* __restrict__ dst){
  int idx = blockIdx.x*256 + threadIdx.x;   // 5*512*128 float4 jobs
  if (idx >= 5*512*128) return;
  int c = idx >> 16;
  int rem = idx & 65535;
  int y = rem >> 7, xq = rem & 127;
  float4 v = *(const float4*)&src[c*262144 + y*512 + 4*xq];
  float* d = &dst[c*(514*516) + (y+1)*516 + 1 + 4*xq];
  d[0]=v.x; d[1]=v.y; d[2]=v.z; d[3]=v.w;
}

// sum fp32 partials over splits, then bias + relu + maxpool2x2 (unpadded out)
template<int SPLITK>
__global__ __launch_bounds__(256) void reduce_pool(
    const float* __restrict__ pbuf, const float* __restrict__ bias,
    float* __restrict__ out, int COUT, int H, int W)
{
  int idx = blockIdx.x*256 + threadIdx.x;
  const int OW = W >> 1, OH = H >> 1;
  if (idx >= COUT*OH*OW) return;
  int px = idx % OW; int t = idx / OW; int py = t % OH; int cout = t / OH;
  unsigned base = (unsigned)cout*H*W + (unsigned)(2*py)*W + 2*px;
  unsigned sstr = (unsigned)COUT*H*W;
  float s00=0.f, s01=0.f, s10=0.f, s11=0.f;
  #pragma unroll
  for (int s=0;s<SPLITK;s++){
    const float* pb = pbuf + s*sstr + base;
    s00 += pb[0]; s01 += pb[1]; s10 += pb[W]; s11 += pb[W+1];
  }
  float m = fmaxf(fmaxf(s00,s01),fmaxf(s10,s11)) + bias[cout];
  out[idx] = fmaxf(m, 0.f);
}

// ---------------- graph kernels ----------------
__global__ void build_adj_kernel(const int* __restrict__ ei, float* adj, float* cnt){
  int e = blockIdx.x*256 + threadIdx.x;
  if (e < N_EDGES){
    int s = ei[e], d = ei[N_EDGES + e];
    atomicAdd(&adj[s*NN1 + d], 1.0f);   // integer-valued -> order independent
    atomicAdd(&cnt[d], 1.0f);
  }
}

// transpose the 4 sage weight matrices [128][256] -> [256][128], packed
__global__ void transpose4_kernel(const float* __restrict__ a, const float* __restrict__ b,
    const float* __restrict__ c, const float* __restrict__ d, float* __restrict__ o){
  int m = blockIdx.y, k = blockIdx.x, cc = threadIdx.x;  // 128 thr
  const float* src = (m==0)?a:(m==1)?b:(m==2)?c:d;
  o[(size_t)m*32768 + k*128 + cc] = src[cc*256 + k];
}

__global__ __launch_bounds__(256) void agg_kernel(const float* __restrict__ adj,
    const float* __restrict__ cnt, const float* __restrict__ org, float* __restrict__ aggn){
  int d = blockIdx.x, j = threadIdx.x;
  float acc = 0.f;
  for (int s = 0; s < NN1; ++s){
    float a = adj[s*NN1 + d];
    if (a != 0.f) acc += a * org[s*NN1 + j];
  }
  aggn[d*NN1 + j] = acc / fmaxf(cnt[d], 1.0f);
}

// transposed-weight sage12: coalesced weight reads; also writes s^T
__global__ __launch_bounds__(128) void sage12_kernel(
    const float* __restrict__ aggn, const float* __restrict__ org,
    const float* __restrict__ wl1t, const float* __restrict__ bl1, const float* __restrict__ wr1t,
    const float* __restrict__ wl2t, const float* __restrict__ bl2, const float* __restrict__ wr2t,
    float* __restrict__ x1, float* __restrict__ s_out, float* __restrict__ st,
    float* __restrict__ entpart)
{
  __shared__ float sa[NN1], so[NN1], red[128];
  int n = blockIdx.x, c = threadIdx.x;
  for (int k = c; k < NN1; k += 128){ sa[k] = aggn[n*NN1+k]; so[k] = org[n*NN1+k]; }
  __syncthreads();
  float p1 = bl1[c], p2 = bl2[c];
  for (int k = 0; k < NN1; ++k){
    float av = sa[k], ov = so[k];
    p1 += av*wl1t[k*128+c] + ov*wr1t[k*128+c];
    p2 += av*wl2t[k*128+c] + ov*wr2t[k*128+c];
  }
  float n1s = block_sum<128>(p1*p1, red, c);
  x1[n*128 + c] = p1 / fmaxf(sqrtf(n1s), 1e-12f);
  float n2s = block_sum<128>(p2*p2, red, c);
  float p2n = p2 / fmaxf(sqrtf(n2s), 1e-12f);
  float mx = block_max<128>(p2n, red, c);
  float ev = expf(p2n - mx);
  float ssum = block_sum<128>(ev, red, c);
  float sv = ev / ssum;
  s_out[n*128 + c] = sv;
  st[c*NN1 + n] = sv;
  float esum = block_sum<128>(-sv * logf(sv + 1e-15f), red, c);
  if (c == 0) entpart[n] = esum;
}

__global__ __launch_bounds__(128) void xp_kernel(const float* __restrict__ s,
    const float* __restrict__ x1, float* __restrict__ xp){
  int cc = blockIdx.x, f = threadIdx.x;
  float acc = 0.f;
  for (int n = 0; n < NN1; ++n) acc += s[n*128+cc] * x1[n*128+f];
  xp[cc*128+f] = acc;
}

__global__ __launch_bounds__(128) void adj_s_kernel(const float* __restrict__ adj,
    const float* __restrict__ s, float* __restrict__ t){
  int n = blockIdx.x, c = threadIdx.x;
  float acc = 0.f;
  for (int m = 0; m < NN1; ++m){
    float a = adj[n*NN1+m];
    if (a != 0.f) acc += a * s[m*128+c];
  }
  t[n*128+c] = acc;
}

__global__ __launch_bounds__(128) void adjp_kernel(const float* __restrict__ s,
    const float* __restrict__ t, float* __restrict__ adjp){
  int cc = blockIdx.x, d = threadIdx.x;
  float acc = 0.f;
  for (int n = 0; n < NN1; ++n) acc += s[n*128+cc] * t[n*128+d];
  adjp[cc*128+d] = acc;
}

// per-row n: sum_m (adj[n][m] - s[n]·s[m])^2 ; uses s^T for coalesced reads
__global__ __launch_bounds__(256) void link_kernel(const float* __restrict__ adj,
    const float* __restrict__ s, const float* __restrict__ st, float* __restrict__ linkpart){
  __shared__ float sn[128]; __shared__ float red[256];
  int n = blockIdx.x, m = threadIdx.x;
  if (m < 128) sn[m] = s[n*128+m];
  __syncthreads();
  float dot = 0.f;
  for (int c = 0; c < 128; ++c) dot += sn[c]*st[c*NN1 + m];
  float v = adj[n*NN1+m] - dot;
  float part = block_sum<256>(v*v, red, m);
  if (m == 0) linkpart[n] = part;
}

__global__ __launch_bounds__(128) void binarize_kernel(const float* __restrict__ adjp,
    float* __restrict__ edge_out, float* __restrict__ ei2_out, int* __restrict__ cols){
  __shared__ float red[128]; __shared__ int redi[128];
  int i = blockIdx.x, j = threadIdx.x;
  float v = adjp[i*128+j];
  float mx = block_max<128>(v, red, j);
  edge_out[i*128+j] = (v == mx) ? 1.0f : 0.0f;
  int cand = (v == mx) ? j : (1 << 30);
  int cmin = block_min_int<128>(cand, redi, j);
  if (j == 0){
    cols[i] = cmin;
    ei2_out[i] = (float)i;
    ei2_out[128 + i] = (float)cmin;
  }
}

__global__ __launch_bounds__(128) void sage3_agg_kernel(const float* __restrict__ xp,
    const int* __restrict__ cols, float* __restrict__ aggn3){
  int d = blockIdx.x, f = threadIdx.x;
  float acc = 0.f, c = 0.f;
  for (int i = 0; i < NN2; ++i){
    if (cols[i] == d){ acc += xp[i*128+f]; c += 1.f; }
  }
  aggn3[d*128+f] = acc / fmaxf(c, 1.f);
}

__global__ __launch_bounds__(128) void sage3_out_kernel(const float* __restrict__ aggn3,
    const float* __restrict__ xp,
    const float* __restrict__ wl3, const float* __restrict__ bl3, const float* __restrict__ wr3,
    float* __restrict__ nodes_out)
{
  __shared__ float red[128];
  int n = blockIdx.x, k = threadIdx.x;
  float ag = aggn3[n*128+k];
  float xv = xp[n*128+k];
  float q0 = block_sum<128>(ag*wl3[k]     + xv*wr3[k],     red, k);
  float q1 = block_sum<128>(ag*wl3[128+k] + xv*wr3[128+k], red, k);
  if (k == 0){
    float p0 = q0 + bl3[0], p1 = q1 + bl3[1];
    float nm = fmaxf(sqrtf(p0*p0 + p1*p1), 1e-12f);
    nodes_out[n*2+0] = tanhf(p0/nm);
    nodes_out[n*2+1] = tanhf(p1/nm);
  }
}

__global__ __launch_bounds__(256) void finalize_kernel(const float* __restrict__ linkpart,
    const float* __restrict__ entpart, float* __restrict__ d_out)
{
  __shared__ float red[256];
  int t = threadIdx.x;
  float ls = block_sum<256>(linkpart[t], red, t);
  float es = block_sum<256>(entpart[t], red, t);
  float v0 = 0.f, v1 = 0.f;
  if (t < 128){ v0 = d_out[4 + t*2 + 0]; v1 = d_out[4 + t*2 + 1]; }
  float s0 = block_sum<256>(v0, red, t);
  float s1 = block_sum<256>(v1, red, t);
  if (t == 0){
    d_out[0] = s0;
    d_out[1] = s1;
    d_out[2] = sqrtf(ls)/65536.0f + sqrtf(16256.0f)/16384.0f;  // ll1 + ll2(const)
    d_out[3] = es/256.0f;                                      // el1 + el2(=0)
  }
}

extern "C" void kernel_launch(void* const* d_in, const int* in_sizes, int n_in,
                              void* d_out_v, int out_size, void* d_ws, size_t ws_size,
                              hipStream_t stream)
{
  (void)in_sizes; (void)n_in; (void)out_size; (void)ws_size;
  const float* input = (const float*)d_in[0];
  const int*   ei    = (const int*)  d_in[1];
  const float* w1 = (const float*)d_in[2];  const float* b1 = (const float*)d_in[3];
  const float* w2 = (const float*)d_in[4];  const float* b2 = (const float*)d_in[5];
  const float* w3 = (const float*)d_in[6];  const float* b3 = (const float*)d_in[7];
  const float* w4 = (const float*)d_in[8];  const float* b4 = (const float*)d_in[9];
  const float* w5 = (const float*)d_in[10]; const float* b5 = (const float*)d_in[11];
  const float* s1wl = (const float*)d_in[12]; const float* s1bl = (const float*)d_in[13];
  const float* s1wr = (const float*)d_in[14];
  const float* s2wl = (const float*)d_in[15]; const float* s2bl = (const float*)d_in[16];
  const float* s2wr = (const float*)d_in[17];
  const float* s3wl = (const float*)d_in[18]; const float* s3bl = (const float*)d_in[19];
  const float* s3wr = (const float*)d_in[20];
  float* d_out = (float*)d_out_v;
  float* ws = (float*)d_ws;

  // Padded buffers [C][H+2][row], row = W+2 padded to x4; interior at +row+1.
  // P1: 32x258x260  P2: 64x130x132  P3: 128x66x68  P4: 256x34x36
  float* P1 = ws;                     // 2,146,560
  float* P2 = ws + 2146560;           // 1,098,240 (graph scratch + P0 alias)
  float* P3 = ws + 3244800;           //   574,464
  float* P4 = ws + 3819264;           //   313,344
  float* org = ws + 4132608;          //    65,536
  float* PART = P1;                   // L5 partials: 8x256x32x32 = 2,097,152 (P1 dead after L2)
  float* P0 = P2;                     // padded input 5x514x516 = 1,326,120 (dead after L1;
                                      //  spans P2+part of P3, both written later)

  // graph scratch (after convs) aliases P2 region
  float* G        = P2;
  float* adj1     = G;                   // 65,536
  float* cnt      = G + 65536;           // 256
  float* aggn3    = G + 65792;           // 16,384
  float* aggn     = G + 82176;           // 65,536
  float* x1       = G + 147712;          // 32,768
  float* s        = G + 180480;          // 32,768
  float* t        = G + 213248;          // 32,768
  float* xp       = G + 246016;          // 16,384
  float* adjp     = G + 262400;          // 16,384
  int*   cols     = (int*)(G + 278784);  // 128
  float* linkpart = G + 278912;          // 256
  float* entpart  = G + 279168;          // 256
  float* wt       = G + 279424;          // 4 x 32,768 transposed sage weights
  float* st       = G + 410496;          // 32,768 (s^T)

  const int p1r = 260, p1c = 258*260;
  const int p2r = 132, p2c = 130*132;
  const int p3r = 68,  p3c = 66*68;
  const int p4r = 36,  p4c = 34*36;
  const int p0r = 516, p0c = 514*516;

  // zero padded buffers (borders must be 0 every launch; interiors overwritten)
  hipMemsetAsync(ws, 0, (size_t)4132608*sizeof(float), stream);
  pad_copy<<<dim3(1280), 256, 0, stream>>>(input, P0);

  // L1: 5->32 @512 -> P1 interior                          (2048 blocks)
  conv7<5,32,16,5,1>   <<<dim3(32,32,2),  256, 0, stream>>>(P0, w1, b1, P1+p1r+1, 512,512, p0r,p0c, p1r,p1c);
  // L2: 32->64 @256 -> P2 interior                         (1024 blocks)
  conv7<32,64,16,4,1>  <<<dim3(16,16,4),  256, 0, stream>>>(P1, w2, b2, P2+p2r+1, 256,256, p1r,p1c, p2r,p2c);
  // L3: 64->128 @128 -> P3 interior                        (512 blocks)
  conv7<64,128,16,4,1> <<<dim3(8,8,8),    256, 0, stream>>>(P2, w3, b3, P3+p3r+1, 128,128, p2r,p2c, p3r,p3c);
  // L4: 128->256 @64, NC=8 -> P4 interior                  (512 blocks, input L2-resident)
  conv7<128,256,8,4,1> <<<dim3(4,4,32),   256, 0, stream>>>(P3, w4, b4, P4+p4r+1, 64,64, p3r,p3c, p4r,p4c);
  // L5: 256->256 @32, NC=8 splitK8 -> PART, reduce -> org  (1024 blocks)
  conv7<256,256,8,4,8> <<<dim3(2,2,256),  256, 0, stream>>>(P4, w5, b5, PART, 32,32, p4r,p4c, 0,0);
  reduce_pool<8>       <<<dim3(256),      256, 0, stream>>>(PART, b5, org, 256, 32, 32);

  // graph tail
  hipMemsetAsync(adj1, 0, (65536 + 256)*sizeof(float), stream);
  transpose4_kernel<<<dim3(256,4), 128, 0, stream>>>(s1wl, s1wr, s2wl, s2wr, wt);
  build_adj_kernel<<<dim3(16),  256, 0, stream>>>(ei, adj1, cnt);
  agg_kernel      <<<dim3(256), 256, 0, stream>>>(adj1, cnt, org, aggn);
  sage12_kernel   <<<dim3(256), 128, 0, stream>>>(aggn, org, wt, s1bl, wt+32768,
                                                  wt+65536, s2bl, wt+98304, x1, s, st, entpart);
  xp_kernel       <<<dim3(128), 128, 0, stream>>>(s, x1, xp);
  adj_s_kernel    <<<dim3(256), 128, 0, stream>>>(adj1, s, t);
  adjp_kernel     <<<dim3(128), 128, 0, stream>>>(s, t, adjp);
  link_kernel     <<<dim3(256), 256, 0, stream>>>(adj1, s, st, linkpart);
  binarize_kernel <<<dim3(128), 128, 0, stream>>>(adjp, d_out + 260, d_out + 16644, cols);
  sage3_agg_kernel<<<dim3(128), 128, 0, stream>>>(xp, cols, aggn3);
  sage3_out_kernel<<<dim3(128), 128, 0, stream>>>(aggn3, xp, s3wl, s3bl, s3wr, d_out + 4);
  finalize_kernel <<<dim3(1),   256, 0, stream>>>(linkpart, entpart, d_out);
}

// Round 8
// 448.125 us; speedup vs baseline: 4.0312x; 1.0005x over previous
//
#include <hip/hip_runtime.h>
#include <math.h>

#define N_EDGES 4096
#define NN1 256
#define NN2 128

// ---------------- reduction helpers ----------------
template<int NT>
__device__ inline float block_sum(float v, float* red, int t){
  red[t] = v; __syncthreads();
  #pragma unroll
  for (int st = NT/2; st > 0; st >>= 1){
    if (t < st) red[t] += red[t+st];
    __syncthreads();
  }
  float r = red[0]; __syncthreads();
  return r;
}
template<int NT>
__device__ inline float block_max(float v, float* red, int t){
  red[t] = v; __syncthreads();
  #pragma unroll
  for (int st = NT/2; st > 0; st >>= 1){
    if (t < st) red[t] = fmaxf(red[t], red[t+st]);
    __syncthreads();
  }
  float r = red[0]; __syncthreads();
  return r;
}
template<int NT>
__device__ inline int block_min_int(int v, int* red, int t){
  red[t] = v; __syncthreads();
  #pragma unroll
  for (int st = NT/2; st > 0; st >>= 1){
    if (t < st) red[t] = min(red[t], red[t+st]);
    __syncthreads();
  }
  int r = red[0]; __syncthreads();
  return r;
}

// ---------------- conv3x3(SAME), dbuf register-prefetch, 1 barrier/chunk ----------------
// Block 256 thr = 4 waves; tile = 16x16 conv (8x8 pooled). NC couts/block,
// wave owns CPT=NC/4 couts, thread computes CPT x 4 conv pts.
// Input MUST be pre-padded: [CIN][H+2][in_row], zero border.
// grid = (CGRPS * W/16, H/16, SPLITK); cout-group is the FASTEST-varying index
// so same-tile re-reads across cout groups are temporally adjacent (cache-hit).
// Pipeline per chunk: LD(next->regs) | COMPUTE(cur) | ST(next->LDS) | barrier.
// Two LDS buffers make one barrier per chunk sufficient.
// SPLITK==1: fused bias+relu+pool -> padded interior out pointer.
// SPLITK>1 : raw conv partials [split][COUT][H][W].
template<int CIN, int COUT, int NC, int CHUNK, int SPLITK>
__global__ __launch_bounds__(256) void conv8(
    const float* __restrict__ in, const float* __restrict__ w,
    const float* __restrict__ bias, float* __restrict__ out,
    int H, int W, int in_row, int in_ch, int out_row, int out_ch)
{
  constexpr int CPB  = CIN / SPLITK;
  constexpr int NCH  = CPB / CHUNK;
  constexpr int CPT  = NC / 4;
  constexpr int TROW = 28;
  constexpr int CGRPS = COUT / NC;
  constexpr int TSZ  = CHUNK * 18 * TROW;
  constexpr int WSZ  = CHUNK * NC * 12;
  constexpr int TJ   = CHUNK * 90;          // float4 tile jobs
  constexpr int WN   = CHUNK * NC * 9;      // weight scalar jobs
  __shared__ float tile[2][TSZ];
  __shared__ float wlds[2][WSZ];

  const int cg = blockIdx.x % CGRPS;        // fastest-varying: cache locality
  const int bx = blockIdx.x / CGRPS;
  const int by = blockIdx.y;
  const int split = blockIdx.z;
  const int tid = threadIdx.x;
  const int lane = tid & 63;
  const int wv = tid >> 6;
  const int px = lane & 7, py = lane >> 3;
  const int c_base = split * CPB;

  // ---- hoisted staging descriptors (chunk-invariant) ----
  int tsrc0, tlds0, tsrc1 = 0, tlds1 = 0;
  {
    int j = tid, row = j / 5, part = j - row*5, c = row / 18, rr = row - c*18;
    tsrc0 = (c_base + c)*in_ch + (16*by + rr)*in_row + 16*bx + 4*part;
    tlds0 = (c*18 + rr)*TROW + 4*part;
  }
  const bool tv1 = (tid + 256) < TJ;
  if (tv1){
    int j = tid + 256, row = j / 5, part = j - row*5, c = row / 18, rr = row - c*18;
    tsrc1 = (c_base + c)*in_ch + (16*by + rr)*in_row + 16*bx + 4*part;
    tlds1 = (c*18 + rr)*TROW + 4*part;
  }
  int wsrc0, wldo0, wsrc1 = 0, wldo1 = 0, wsrc2 = 0, wldo2 = 0;
  {
    int e = tid, c = e/(NC*9), r = e - c*NC*9, co = r/9, k = r - co*9;
    wsrc0 = ((cg*NC + co)*CIN + c_base + c)*9 + k;
    wldo0 = (c*NC + co)*12 + k;
  }
  const bool wq1 = (tid + 256) < WN;
  if (wq1){
    int e = tid + 256, c = e/(NC*9), r = e - c*NC*9, co = r/9, k = r - co*9;
    wsrc1 = ((cg*NC + co)*CIN + c_base + c)*9 + k;
    wldo1 = (c*NC + co)*12 + k;
  }
  const bool wq2 = (tid + 512) < WN;
  if (wq2){
    int e = tid + 512, c = e/(NC*9), r = e - c*NC*9, co = r/9, k = r - co*9;
    wsrc2 = ((cg*NC + co)*CIN + c_base + c)*9 + k;
    wldo2 = (c*NC + co)*12 + k;
  }

  float acc[CPT][4];
  #pragma unroll
  for (int co = 0; co < CPT; ++co){
    acc[co][0]=0.f; acc[co][1]=0.f; acc[co][2]=0.f; acc[co][3]=0.f;
  }

  float4 rt0, rt1;
  float rw0, rw1, rw2;

  auto LD = [&](int c0){
    rt0 = *(const float4*)&in[tsrc0 + c0*in_ch];
    if (tv1) rt1 = *(const float4*)&in[tsrc1 + c0*in_ch];
    rw0 = w[wsrc0 + c0*9];
    if (wq1) rw1 = w[wsrc1 + c0*9];
    if (wq2) rw2 = w[wsrc2 + c0*9];
  };
  auto ST = [&](int b){
    *(float4*)&tile[b][tlds0] = rt0;
    if (tv1) *(float4*)&tile[b][tlds1] = rt1;
    wlds[b][wldo0] = rw0;
    if (wq1) wlds[b][wldo1] = rw1;
    if (wq2) wlds[b][wldo2] = rw2;
  };
  auto COMPUTE = [&](int b){
    #pragma unroll
    for (int c = 0; c < CHUNK; ++c){
      float p[4][4];
      const int tb = c*18*TROW + 2*py*TROW + 2*px;
      #pragma unroll
      for (int i = 0; i < 4; ++i){
        float2 lo = *(const float2*)&tile[b][tb + i*TROW];
        float2 hi = *(const float2*)&tile[b][tb + i*TROW + 2];
        p[i][0]=lo.x; p[i][1]=lo.y; p[i][2]=hi.x; p[i][3]=hi.y;
      }
      #pragma unroll
      for (int co = 0; co < CPT; ++co){
        const float* wp = &wlds[b][(c*NC + wv*CPT + co)*12];
        float4 qa = *(const float4*)&wp[0];
        float4 qb = *(const float4*)&wp[4];
        float w8 = wp[8];
        acc[co][0] += qa.x*p[0][0]+qa.y*p[0][1]+qa.z*p[0][2] + qa.w*p[1][0]+qb.x*p[1][1]+qb.y*p[1][2] + qb.z*p[2][0]+qb.w*p[2][1]+w8*p[2][2];
        acc[co][1] += qa.x*p[0][1]+qa.y*p[0][2]+qa.z*p[0][3] + qa.w*p[1][1]+qb.x*p[1][2]+qb.y*p[1][3] + qb.z*p[2][1]+qb.w*p[2][2]+w8*p[2][3];
        acc[co][2] += qa.x*p[1][0]+qa.y*p[1][1]+qa.z*p[1][2] + qa.w*p[2][0]+qb.x*p[2][1]+qb.y*p[2][2] + qb.z*p[3][0]+qb.w*p[3][1]+w8*p[3][2];
        acc[co][3] += qa.x*p[1][1]+qa.y*p[1][2]+qa.z*p[1][3] + qa.w*p[2][1]+qb.x*p[2][2]+qb.y*p[2][3] + qb.z*p[3][1]+qb.w*p[3][2]+w8*p[3][3];
      }
    }
  };

  LD(0); ST(0); __syncthreads();
  for (int ch = 0; ch < NCH; ++ch){
    if (ch + 1 < NCH) LD((ch+1)*CHUNK);   // global loads in flight under compute
    COMPUTE(ch & 1);
    if (ch + 1 < NCH){
      ST((ch+1) & 1);                     // other waves are in COMPUTE(cur buf) - safe
      __syncthreads();                    // single barrier per chunk
    }
  }

  if (SPLITK == 1){
    #pragma unroll
    for (int co = 0; co < CPT; ++co){
      int cout = cg*NC + wv*CPT + co;
      float m = fmaxf(fmaxf(acc[co][0],acc[co][1]), fmaxf(acc[co][2],acc[co][3])) + bias[cout];
      int oy = 8*by + py, ox = 8*bx + px;
      out[cout*out_ch + oy*out_row + ox] = fmaxf(m, 0.f);
    }
  } else {
    #pragma unroll
    for (int co = 0; co < CPT; ++co){
      int cout = cg*NC + wv*CPT + co;
      float* pb = out + (split*COUT + cout)*H*W;
      int y0 = 16*by + 2*py, x0 = 16*bx + 2*px;
      *(float2*)&pb[y0*W + x0]     = make_float2(acc[co][0], acc[co][1]);
      *(float2*)&pb[(y0+1)*W + x0] = make_float2(acc[co][2], acc[co][3]);
    }
  }
}

// copy raw 5x512x512 input into zero-bordered P0 [5][514][516]
__global__ __launch_bounds__(256) void pad_copy(const float* __restrict__ src,
                                                float* __restrict__ dst){
  int idx = blockIdx.x*256 + threadIdx.x;   // 5*512*128 float4 jobs
  if (idx >= 5*512*128) return;
  int c = idx >> 16;
  int rem = idx & 65535;
  int y = rem >> 7, xq = rem & 127;
  float4 v = *(const float4*)&src[c*262144 + y*512 + 4*xq];
  float* d = &dst[c*(514*516) + (y+1)*516 + 1 + 4*xq];
  d[0]=v.x; d[1]=v.y; d[2]=v.z; d[3]=v.w;
}

// sum fp32 partials over splits, then bias + relu + maxpool2x2 (unpadded out)
template<int SPLITK>
__global__ __launch_bounds__(256) void reduce_pool(
    const float* __restrict__ pbuf, const float* __restrict__ bias,
    float* __restrict__ out, int COUT, int H, int W)
{
  int idx = blockIdx.x*256 + threadIdx.x;
  const int OW = W >> 1, OH = H >> 1;
  if (idx >= COUT*OH*OW) return;
  int px = idx % OW; int t = idx / OW; int py = t % OH; int cout = t / OH;
  unsigned base = (unsigned)cout*H*W + (unsigned)(2*py)*W + 2*px;
  unsigned sstr = (unsigned)COUT*H*W;
  float s00=0.f, s01=0.f, s10=0.f, s11=0.f;
  #pragma unroll
  for (int s=0;s<SPLITK;s++){
    const float* pb = pbuf + s*sstr + base;
    s00 += pb[0]; s01 += pb[1]; s10 += pb[W]; s11 += pb[W+1];
  }
  float m = fmaxf(fmaxf(s00,s01),fmaxf(s10,s11)) + bias[cout];
  out[idx] = fmaxf(m, 0.f);
}

// ---------------- graph kernels ----------------
__global__ void build_adj_kernel(const int* __restrict__ ei, float* adj, float* cnt){
  int e = blockIdx.x*256 + threadIdx.x;
  if (e < N_EDGES){
    int s = ei[e], d = ei[N_EDGES + e];
    atomicAdd(&adj[s*NN1 + d], 1.0f);   // integer-valued -> order independent
    atomicAdd(&cnt[d], 1.0f);
  }
}

// transpose the 4 sage weight matrices [128][256] -> [256][128], packed
__global__ void transpose4_kernel(const float* __restrict__ a, const float* __restrict__ b,
    const float* __restrict__ c, const float* __restrict__ d, float* __restrict__ o){
  int m = blockIdx.y, k = blockIdx.x, cc = threadIdx.x;  // 128 thr
  const float* src = (m==0)?a:(m==1)?b:(m==2)?c:d;
  o[(size_t)m*32768 + k*128 + cc] = src[cc*256 + k];
}

__global__ __launch_bounds__(256) void agg_kernel(const float* __restrict__ adj,
    const float* __restrict__ cnt, const float* __restrict__ org, float* __restrict__ aggn){
  int d = blockIdx.x, j = threadIdx.x;
  float acc = 0.f;
  for (int s = 0; s < NN1; ++s){
    float a = adj[s*NN1 + d];
    if (a != 0.f) acc += a * org[s*NN1 + j];
  }
  aggn[d*NN1 + j] = acc / fmaxf(cnt[d], 1.0f);
}

// transposed-weight sage12: coalesced weight reads; also writes s^T
__global__ __launch_bounds__(128) void sage12_kernel(
    const float* __restrict__ aggn, const float* __restrict__ org,
    const float* __restrict__ wl1t, const float* __restrict__ bl1, const float* __restrict__ wr1t,
    const float* __restrict__ wl2t, const float* __restrict__ bl2, const float* __restrict__ wr2t,
    float* __restrict__ x1, float* __restrict__ s_out, float* __restrict__ st,
    float* __restrict__ entpart)
{
  __shared__ float sa[NN1], so[NN1], red[128];
  int n = blockIdx.x, c = threadIdx.x;
  for (int k = c; k < NN1; k += 128){ sa[k] = aggn[n*NN1+k]; so[k] = org[n*NN1+k]; }
  __syncthreads();
  float p1 = bl1[c], p2 = bl2[c];
  for (int k = 0; k < NN1; ++k){
    float av = sa[k], ov = so[k];
    p1 += av*wl1t[k*128+c] + ov*wr1t[k*128+c];
    p2 += av*wl2t[k*128+c] + ov*wr2t[k*128+c];
  }
  float n1s = block_sum<128>(p1*p1, red, c);
  x1[n*128 + c] = p1 / fmaxf(sqrtf(n1s), 1e-12f);
  float n2s = block_sum<128>(p2*p2, red, c);
  float p2n = p2 / fmaxf(sqrtf(n2s), 1e-12f);
  float mx = block_max<128>(p2n, red, c);
  float ev = expf(p2n - mx);
  float ssum = block_sum<128>(ev, red, c);
  float sv = ev / ssum;
  s_out[n*128 + c] = sv;
  st[c*NN1 + n] = sv;
  float esum = block_sum<128>(-sv * logf(sv + 1e-15f), red, c);
  if (c == 0) entpart[n] = esum;
}

__global__ __launch_bounds__(128) void xp_kernel(const float* __restrict__ s,
    const float* __restrict__ x1, float* __restrict__ xp){
  int cc = blockIdx.x, f = threadIdx.x;
  float acc = 0.f;
  for (int n = 0; n < NN1; ++n) acc += s[n*128+cc] * x1[n*128+f];
  xp[cc*128+f] = acc;
}

__global__ __launch_bounds__(128) void adj_s_kernel(const float* __restrict__ adj,
    const float* __restrict__ s, float* __restrict__ t){
  int n = blockIdx.x, c = threadIdx.x;
  float acc = 0.f;
  for (int m = 0; m < NN1; ++m){
    float a = adj[n*NN1+m];
    if (a != 0.f) acc += a * s[m*128+c];
  }
  t[n*128+c] = acc;
}

__global__ __launch_bounds__(128) void adjp_kernel(const float* __restrict__ s,
    const float* __restrict__ t, float* __restrict__ adjp){
  int cc = blockIdx.x, d = threadIdx.x;
  float acc = 0.f;
  for (int n = 0; n < NN1; ++n) acc += s[n*128+cc] * t[n*128+d];
  adjp[cc*128+d] = acc;
}

// per-row n: sum_m (adj[n][m] - s[n]·s[m])^2 ; uses s^T for coalesced reads
__global__ __launch_bounds__(256) void link_kernel(const float* __restrict__ adj,
    const float* __restrict__ s, const float* __restrict__ st, float* __restrict__ linkpart){
  __shared__ float sn[128]; __shared__ float red[256];
  int n = blockIdx.x, m = threadIdx.x;
  if (m < 128) sn[m] = s[n*128+m];
  __syncthreads();
  float dot = 0.f;
  for (int c = 0; c < 128; ++c) dot += sn[c]*st[c*NN1 + m];
  float v = adj[n*NN1+m] - dot;
  float part = block_sum<256>(v*v, red, m);
  if (m == 0) linkpart[n] = part;
}

__global__ __launch_bounds__(128) void binarize_kernel(const float* __restrict__ adjp,
    float* __restrict__ edge_out, float* __restrict__ ei2_out, int* __restrict__ cols){
  __shared__ float red[128]; __shared__ int redi[128];
  int i = blockIdx.x, j = threadIdx.x;
  float v = adjp[i*128+j];
  float mx = block_max<128>(v, red, j);
  edge_out[i*128+j] = (v == mx) ? 1.0f : 0.0f;
  int cand = (v == mx) ? j : (1 << 30);
  int cmin = block_min_int<128>(cand, redi, j);
  if (j == 0){
    cols[i] = cmin;
    ei2_out[i] = (float)i;
    ei2_out[128 + i] = (float)cmin;
  }
}

__global__ __launch_bounds__(128) void sage3_agg_kernel(const float* __restrict__ xp,
    const int* __restrict__ cols, float* __restrict__ aggn3){
  int d = blockIdx.x, f = threadIdx.x;
  float acc = 0.f, c = 0.f;
  for (int i = 0; i < NN2; ++i){
    if (cols[i] == d){ acc += xp[i*128+f]; c += 1.f; }
  }
  aggn3[d*128+f] = acc / fmaxf(c, 1.f);
}

__global__ __launch_bounds__(128) void sage3_out_kernel(const float* __restrict__ aggn3,
    const float* __restrict__ xp,
    const float* __restrict__ wl3, const float* __restrict__ bl3, const float* __restrict__ wr3,
    float* __restrict__ nodes_out)
{
  __shared__ float red[128];
  int n = blockIdx.x, k = threadIdx.x;
  float ag = aggn3[n*128+k];
  float xv = xp[n*128+k];
  float q0 = block_sum<128>(ag*wl3[k]     + xv*wr3[k],     red, k);
  float q1 = block_sum<128>(ag*wl3[128+k] + xv*wr3[128+k], red, k);
  if (k == 0){
    float p0 = q0 + bl3[0], p1 = q1 + bl3[1];
    float nm = fmaxf(sqrtf(p0*p0 + p1*p1), 1e-12f);
    nodes_out[n*2+0] = tanhf(p0/nm);
    nodes_out[n*2+1] = tanhf(p1/nm);
  }
}

__global__ __launch_bounds__(256) void finalize_kernel(const float* __restrict__ linkpart,
    const float* __restrict__ entpart, float* __restrict__ d_out)
{
  __shared__ float red[256];
  int t = threadIdx.x;
  float ls = block_sum<256>(linkpart[t], red, t);
  float es = block_sum<256>(entpart[t], red, t);
  float v0 = 0.f, v1 = 0.f;
  if (t < 128){ v0 = d_out[4 + t*2 + 0]; v1 = d_out[4 + t*2 + 1]; }
  float s0 = block_sum<256>(v0, red, t);
  float s1 = block_sum<256>(v1, red, t);
  if (t == 0){
    d_out[0] = s0;
    d_out[1] = s1;
    d_out[2] = sqrtf(ls)/65536.0f + sqrtf(16256.0f)/16384.0f;  // ll1 + ll2(const)
    d_out[3] = es/256.0f;                                      // el1 + el2(=0)
  }
}

extern "C" void kernel_launch(void* const* d_in, const int* in_sizes, int n_in,
                              void* d_out_v, int out_size, void* d_ws, size_t ws_size,
                              hipStream_t stream)
{
  (void)in_sizes; (void)n_in; (void)out_size; (void)ws_size;
  const float* input = (const float*)d_in[0];
  const int*   ei    = (const int*)  d_in[1];
  const float* w1 = (const float*)d_in[2];  const float* b1 = (const float*)d_in[3];
  const float* w2 = (const float*)d_in[4];  const float* b2 = (const float*)d_in[5];
  const float* w3 = (const float*)d_in[6];  const float* b3 = (const float*)d_in[7];
  const float* w4 = (const float*)d_in[8];  const float* b4 = (const float*)d_in[9];
  const float* w5 = (const float*)d_in[10]; const float* b5 = (const float*)d_in[11];
  const float* s1wl = (const float*)d_in[12]; const float* s1bl = (const float*)d_in[13];
  const float* s1wr = (const float*)d_in[14];
  const float* s2wl = (const float*)d_in[15]; const float* s2bl = (const float*)d_in[16];
  const float* s2wr = (const float*)d_in[17];
  const float* s3wl = (const float*)d_in[18]; const float* s3bl = (const float*)d_in[19];
  const float* s3wr = (const float*)d_in[20];
  float* d_out = (float*)d_out_v;
  float* ws = (float*)d_ws;

  // Padded buffers [C][H+2][row], row = W+2 padded to x4; interior at +row+1.
  // P1: 32x258x260  P2: 64x130x132  P3: 128x66x68  P4: 256x34x36
  // P0 (padded input 5x514x516) has its OWN region - no overlap with P3 (r7 bug fix).
  float* P1  = ws;                    // 2,146,560
  float* P2  = ws + 2146560;          // 1,098,240 (graph scratch aliases after L3)
  float* P3  = ws + 3244800;          //   574,464
  float* P4  = ws + 3819264;          //   313,344
  float* org = ws + 4132608;          //    65,536
  float* P0  = ws + 4198144;          // 1,326,120  (total 5,524,264 floats = 22.1 MB)
  float* PART = P1;                   // L5 partials: 8x256x32x32 = 2,097,152 (P1 dead after L2)

  // graph scratch (after convs) aliases P2 region
  float* G        = P2;
  float* adj1     = G;                   // 65,536
  float* cnt      = G + 65536;           // 256
  float* aggn3    = G + 65792;           // 16,384
  float* aggn     = G + 82176;           // 65,536
  float* x1       = G + 147712;          // 32,768
  float* s        = G + 180480;          // 32,768
  float* t        = G + 213248;          // 32,768
  float* xp       = G + 246016;          // 16,384
  float* adjp     = G + 262400;          // 16,384
  int*   cols     = (int*)(G + 278784);  // 128
  float* linkpart = G + 278912;          // 256
  float* entpart  = G + 279168;          // 256
  float* wt       = G + 279424;          // 4 x 32,768 transposed sage weights
  float* st       = G + 410496;          // 32,768 (s^T)

  const int p1r = 260, p1c = 258*260;
  const int p2r = 132, p2c = 130*132;
  const int p3r = 68,  p3c = 66*68;
  const int p4r = 36,  p4c = 34*36;
  const int p0r = 516, p0c = 514*516;

  // zero all padded buffers incl. P0 (borders must be 0; interiors overwritten)
  hipMemsetAsync(ws, 0, (size_t)5524264*sizeof(float), stream);
  pad_copy<<<dim3(1280), 256, 0, stream>>>(input, P0);

  // L1: 5->32 @512 -> P1 interior    (CGRPS=2,  2048 blocks)
  conv8<5,32,16,5,1>   <<<dim3(2*32,32,1),  256, 0, stream>>>(P0, w1, b1, P1+p1r+1, 512,512, p0r,p0c, p1r,p1c);
  // L2: 32->64 @256 -> P2 interior   (CGRPS=4,  1024 blocks)
  conv8<32,64,16,4,1>  <<<dim3(4*16,16,1),  256, 0, stream>>>(P1, w2, b2, P2+p2r+1, 256,256, p1r,p1c, p2r,p2c);
  // L3: 64->128 @128 -> P3 interior  (CGRPS=8,  512 blocks)
  conv8<64,128,16,4,1> <<<dim3(8*8,8,1),    256, 0, stream>>>(P2, w3, b3, P3+p3r+1, 128,128, p2r,p2c, p3r,p3c);
  // L4: 128->256 @64 -> P4 interior  (CGRPS=32, 512 blocks)
  conv8<128,256,8,4,1> <<<dim3(32*4,4,1),   256, 0, stream>>>(P3, w4, b4, P4+p4r+1, 64,64, p3r,p3c, p4r,p4c);
  // L5: 256->256 @32 splitK8 -> PART, reduce -> org (CGRPS=32, 1024 blocks)
  conv8<256,256,8,4,8> <<<dim3(32*2,2,8),   256, 0, stream>>>(P4, w5, b5, PART, 32,32, p4r,p4c, 0,0);
  reduce_pool<8>       <<<dim3(256),        256, 0, stream>>>(PART, b5, org, 256, 32, 32);

  // graph tail
  hipMemsetAsync(adj1, 0, (65536 + 256)*sizeof(float), stream);
  transpose4_kernel<<<dim3(256,4), 128, 0, stream>>>(s1wl, s1wr, s2wl, s2wr, wt);
  build_adj_kernel<<<dim3(16),  256, 0, stream>>>(ei, adj1, cnt);
  agg_kernel      <<<dim3(256), 256, 0, stream>>>(adj1, cnt, org, aggn);
  sage12_kernel   <<<dim3(256), 128, 0, stream>>>(aggn, org, wt, s1bl, wt+32768,
                                                  wt+65536, s2bl, wt+98304, x1, s, st, entpart);
  xp_kernel       <<<dim3(128), 128, 0, stream>>>(s, x1, xp);
  adj_s_kernel    <<<dim3(256), 128, 0, stream>>>(adj1, s, t);
  adjp_kernel     <<<dim3(128), 128, 0, stream>>>(s, t, adjp);
  link_kernel     <<<dim3(256), 256, 0, stream>>>(adj1, s, st, linkpart);
  binarize_kernel <<<dim3(128), 128, 0, stream>>>(adjp, d_out + 260, d_out + 16644, cols);
  sage3_agg_kernel<<<dim3(128), 128, 0, stream>>>(xp, cols, aggn3);
  sage3_out_kernel<<<dim3(128), 128, 0, stream>>>(aggn3, xp, s3wl, s3bl, s3wr, d_out + 4);
  finalize_kernel <<<dim3(1),   256, 0, stream>>>(linkpart, entpart, d_out);
}